// Round 14
// baseline (129.317 us; speedup 1.0000x reference)
//
#include <hip/hip_runtime.h>
#include <hip/hip_cooperative_groups.h>
#include <math.h>

namespace cg = cooperative_groups;

#define BB 4
#define NSZ 2048
#define FDIM 128
#define ODIM 32
#define HH 8

typedef _Float16 half8 __attribute__((ext_vector_type(8)));
typedef float f32x4 __attribute__((ext_vector_type(4)));

// workspace layout (float units)
#define WS_EAP  0                 // float[B*H*N]  R_i = exp(-0.8 a_i)
#define WS_EBP  131072            // f16 EB[B*H*N] + f16 EB2[B*H*N]
#define WS_ADJB 262144            // u32[B*N*64]
#define WS_WHF  786432            // f16 Wh B-frags (4MB)
// whf: int4[((b*H+h)*64 + jt)*2 + ot][64 lanes]

// pack 2 f32 -> 2 f16 (RTZ) in one dword
__device__ __forceinline__ unsigned hpack(float a, float b) {
    unsigned r;
    asm("v_cvt_pkrtz_f16_f32 %0, %1, %2" : "=v"(r) : "v"(a), "v"(b));
    return r;
}

// masked q-fragment, f16 packed: q = max(EB, R*EB2) via 4x v_pk_mul_f16 +
// 4x v_pk_max_f16; mask via 16-entry LDS LUT (2x ds_read_b64 + 4 AND).
__device__ __forceinline__ int4 pfrag16(unsigned R2, uint4 e, uint4 g,
                                        unsigned w8,
                                        const unsigned (*__restrict__ mlut)[2]) {
    unsigned r0, r1, r2, r3, q0, q1, q2, q3;
    asm("v_pk_mul_f16 %0, %1, %2" : "=v"(r0) : "v"(R2), "v"(g.x));
    asm("v_pk_mul_f16 %0, %1, %2" : "=v"(r1) : "v"(R2), "v"(g.y));
    asm("v_pk_mul_f16 %0, %1, %2" : "=v"(r2) : "v"(R2), "v"(g.z));
    asm("v_pk_mul_f16 %0, %1, %2" : "=v"(r3) : "v"(R2), "v"(g.w));
    asm("v_pk_max_f16 %0, %1, %2" : "=v"(q0) : "v"(e.x), "v"(r0));
    asm("v_pk_max_f16 %0, %1, %2" : "=v"(q1) : "v"(e.y), "v"(r1));
    asm("v_pk_max_f16 %0, %1, %2" : "=v"(q2) : "v"(e.z), "v"(r2));
    asm("v_pk_max_f16 %0, %1, %2" : "=v"(q3) : "v"(e.w), "v"(r3));
    const unsigned* mA = mlut[w8 & 15];
    const unsigned* mB = mlut[(w8 >> 4) & 15];
    return make_int4((int)(q0 & mA[0]), (int)(q1 & mA[1]),
                     (int)(q2 & mB[0]), (int)(q3 & mB[1]));
}

// ===========================================================================
// FALLBACK PATH (exact R12 two-kernel structure, known-good 129.3us)
// ===========================================================================
__global__ __launch_bounds__(256) void k_prep(const float* __restrict__ x,
                                              const float* __restrict__ adj,
                                              const float* __restrict__ W,
                                              const float* __restrict__ a_src,
                                              const float* __restrict__ a_dst,
                                              unsigned* __restrict__ adjb,
                                              int4* __restrict__ whf,
                                              float* __restrict__ eap,
                                              unsigned short* __restrict__ ebe,
                                              unsigned short* __restrict__ ebe2) {
    __shared__ float wsl[FDIM * 33];
    __shared__ unsigned short wlds[64][33];
    int t = threadIdx.x;

    if (blockIdx.x >= 1024) {
        int bid = blockIdx.x - 1024;
#pragma unroll
        for (int it = 0; it < 4; it++) {
            int g = (it * 4096 + bid) * 256 + t;
            int l = g & 7;
            int word = g >> 3;
            int wk = word & 63;
            int row = word >> 6;
            int i = row & (NSZ - 1);
            const float4 v = *(const float4*)&adj[(size_t)row * NSZ + wk * 32 + l * 4];
            unsigned m = 0;
            if (v.x > 0.f) m |= 1u << (l * 4 + 0);
            if (v.y > 0.f) m |= 1u << (l * 4 + 1);
            if (v.z > 0.f) m |= 1u << (l * 4 + 2);
            if (v.w > 0.f) m |= 1u << (l * 4 + 3);
            m |= (unsigned)__shfl_xor((int)m, 1);
            m |= (unsigned)__shfl_xor((int)m, 2);
            m |= (unsigned)__shfl_xor((int)m, 4);
            if (l == 0) {
                int jb = i - wk * 32;
                if (jb >= 0 && jb < 32) m |= 1u << jb;
                adjb[word] = m;
            }
        }
        return;
    }

    int bidx = blockIdx.x;
    int b = bidx >> 8;
    int h = (bidx >> 5) & 7;
    int nt = bidx & 31;
    int n0 = nt * 64;
    int w = t >> 6, lane = t & 63;
    int col = lane & 15, quad = lane >> 4;

#pragma unroll
    for (int m = 0; m < 16; m++) {
        int idx = t + m * 256;
        wsl[(idx >> 5) * 33 + (idx & 31)] = W[(size_t)h * (FDIM * ODIM) + idx];
    }

    const float* xp = x + ((size_t)(b * NSZ) + n0 + w * 16 + col) * FDIM + quad * 8;
    int4 afr[4];
#pragma unroll
    for (int kt = 0; kt < 4; kt++) {
        float4 xa = *(const float4*)(xp + kt * 32);
        float4 xb = *(const float4*)(xp + kt * 32 + 4);
        afr[kt] = make_int4((int)hpack(xa.x, xa.y), (int)hpack(xa.z, xa.w),
                            (int)hpack(xb.x, xb.y), (int)hpack(xb.z, xb.w));
    }
    __syncthreads();

    f32x4 alo = {0.f, 0.f, 0.f, 0.f};
    f32x4 ahi = {0.f, 0.f, 0.f, 0.f};
#pragma unroll
    for (int kt = 0; kt < 4; kt++) {
        half8 a8 = __builtin_bit_cast(half8, afr[kt]);
#pragma unroll
        for (int ot = 0; ot < 2; ot++) {
            unsigned d[4];
#pragma unroll
            for (int jp = 0; jp < 4; jp++) {
                float lo = wsl[(kt * 32 + quad * 8 + 2 * jp) * 33 + ot * 16 + col];
                float hi = wsl[(kt * 32 + quad * 8 + 2 * jp + 1) * 33 + ot * 16 + col];
                d[jp] = hpack(lo, hi);
            }
            int4 bf = make_int4((int)d[0], (int)d[1], (int)d[2], (int)d[3]);
            if (ot == 0)
                alo = __builtin_amdgcn_mfma_f32_16x16x32_f16(a8,
                        __builtin_bit_cast(half8, bf), alo, 0, 0, 0);
            else
                ahi = __builtin_amdgcn_mfma_f32_16x16x32_f16(a8,
                        __builtin_bit_cast(half8, bf), ahi, 0, 0, 0);
        }
    }

    float as0 = a_src[h * ODIM + col], as1 = a_src[h * ODIM + 16 + col];
    float ad0 = a_dst[h * ODIM + col], ad1 = a_dst[h * ODIM + 16 + col];
#pragma unroll
    for (int r = 0; r < 4; r++) {
        float pa = alo[r] * as0 + ahi[r] * as1;
        float pb = alo[r] * ad0 + ahi[r] * ad1;
#pragma unroll
        for (int mk = 1; mk <= 8; mk <<= 1) {
            pa += __shfl_xor(pa, mk);
            pb += __shfl_xor(pb, mk);
        }
        if (col == 0) {
            size_t idx = (size_t)(b * HH + h) * NSZ + n0 + w * 16 + quad * 4 + r;
            eap[idx]  = __expf(-0.8f * pa);
            ebe[idx]  = (unsigned short)(hpack(__expf(pb - 2.f), 0.f) & 0xffffu);
            ebe2[idx] = (unsigned short)(hpack(__expf(0.2f * pb - 2.f), 0.f) & 0xffffu);
        }
    }

#pragma unroll
    for (int r = 0; r < 4; r++) {
        wlds[w * 16 + quad * 4 + r][col]      = (unsigned short)(hpack(alo[r], 0.f) & 0xffffu);
        wlds[w * 16 + quad * 4 + r][col + 16] = (unsigned short)(hpack(ahi[r], 0.f) & 0xffffu);
    }
    __syncthreads();
    int jl = w >> 1, ot = w & 1;
    unsigned d[4];
#pragma unroll
    for (int jp = 0; jp < 4; jp++) {
        unsigned lo = wlds[jl * 32 + quad * 8 + 2 * jp][ot * 16 + col];
        unsigned hi = wlds[jl * 32 + quad * 8 + 2 * jp + 1][ot * 16 + col];
        d[jp] = (hi << 16) | lo;
    }
    int fragid = ((b * HH + h) * 64 + nt * 2 + jl) * 2 + ot;
    whf[(size_t)fragid * 64 + lane] = make_int4((int)d[0], (int)d[1], (int)d[2], (int)d[3]);
}

__global__ __launch_bounds__(512, 4) void k_gat(const int4* __restrict__ whf,
                                                const float* __restrict__ eap,
                                                const unsigned short* __restrict__ ebe,
                                                const unsigned short* __restrict__ ebe2,
                                                const unsigned* __restrict__ adjb,
                                                float* __restrict__ out) {
    __shared__ __align__(16) float smem[6144];
    unsigned short* eble = (unsigned short*)smem;
    unsigned short* eblf = (unsigned short*)smem + 2048;
    unsigned (*mlut)[2] = (unsigned (*)[2])(smem + 2048);

    int t = threadIdx.x;
    int u = blockIdx.x;
    int unit = (u & 7) * 128 + (u >> 3);
    int b = unit >> 8;
    int h = (unit >> 5) & 7;
    int i0 = (unit & 31) * 64;
    int wave = t >> 6, lane = t & 63;
    int ih = wave >> 2, jq = wave & 3;
    int col = lane & 15, quad = lane >> 4, qsh = quad * 8;
    size_t bh = (size_t)(b * HH + h);

    if (t < 16) {
        mlut[t][0] = ((t & 1) ? 0x0000FFFFu : 0u) | ((t & 2) ? 0xFFFF0000u : 0u);
        mlut[t][1] = ((t & 4) ? 0x0000FFFFu : 0u) | ((t & 8) ? 0xFFFF0000u : 0u);
    }

    const float4* ege = (const float4*)(ebe + bh * NSZ);
    const float4* egf = (const float4*)(ebe2 + bh * NSZ);
    if (t < 256) ((float4*)eble)[t] = ege[t];
    else         ((float4*)eblf)[t - 256] = egf[t - 256];

    int iw = i0 + ih * 32;
    float Ra = eap[bh * NSZ + iw + col];
    float Rb = eap[bh * NSZ + iw + 16 + col];
    unsigned R20 = hpack(Ra, Ra);
    unsigned R21 = hpack(Rb, Rb);
    const char* mbase = (const char*)(adjb + ((size_t)(b * NSZ) + iw + col) * 64)
                        + (size_t)jq * 64;
    const int4* bfp = whf + bh * 8192 + (size_t)(jq * 16) * 128 + lane;

    f32x4 a00 = {0.f,0.f,0.f,0.f}, a01 = {0.f,0.f,0.f,0.f}, a0d = {0.f,0.f,0.f,0.f};
    f32x4 a10 = {0.f,0.f,0.f,0.f}, a11 = {0.f,0.f,0.f,0.f}, a1d = {0.f,0.f,0.f,0.f};
    const int4 onesv = make_int4(0x3C003C00, 0x3C003C00, 0x3C003C00, 0x3C003C00);
    half8 hones = __builtin_bit_cast(half8, onesv);

    __syncthreads();

    for (int g = 0; g < 4; g++) {
        uint4 m0 = *(const uint4*)(mbase + 0 * 4096 + g * 16);
        uint4 m1 = *(const uint4*)(mbase + 1 * 4096 + g * 16);
        int4 blo[4], bhi[4];
#pragma unroll
        for (int q = 0; q < 4; q++) {
            blo[q] = bfp[(g * 4 + q) * 128];
            bhi[q] = bfp[(g * 4 + q) * 128 + 64];
        }
        unsigned ma0[4] = {m0.x, m0.y, m0.z, m0.w};
        unsigned ma1[4] = {m1.x, m1.y, m1.z, m1.w};
#pragma unroll
        for (int q = 0; q < 4; q++) {
            int jt = jq * 16 + g * 4 + q;
            uint4 ef = *(const uint4*)&eble[jt * 32 + qsh];
            uint4 gf = *(const uint4*)&eblf[jt * 32 + qsh];
            half8 b0 = __builtin_bit_cast(half8, blo[q]);
            half8 b1 = __builtin_bit_cast(half8, bhi[q]);
            int4 f0 = pfrag16(R20, ef, gf, ma0[q] >> qsh, mlut);
            int4 f1 = pfrag16(R21, ef, gf, ma1[q] >> qsh, mlut);
            half8 af0 = __builtin_bit_cast(half8, f0);
            half8 af1 = __builtin_bit_cast(half8, f1);
            a00 = __builtin_amdgcn_mfma_f32_16x16x32_f16(af0, b0, a00, 0, 0, 0);
            a01 = __builtin_amdgcn_mfma_f32_16x16x32_f16(af0, b1, a01, 0, 0, 0);
            a0d = __builtin_amdgcn_mfma_f32_16x16x32_f16(af0, hones, a0d, 0, 0, 0);
            a10 = __builtin_amdgcn_mfma_f32_16x16x32_f16(af1, b0, a10, 0, 0, 0);
            a11 = __builtin_amdgcn_mfma_f32_16x16x32_f16(af1, b1, a11, 0, 0, 0);
            a1d = __builtin_amdgcn_mfma_f32_16x16x32_f16(af1, hones, a1d, 0, 0, 0);
        }
    }

    f32x4 (*cb)[3][64] = (f32x4 (*)[3][64])smem;
    __syncthreads();
    if (jq >= 2) {
        int s = ih * 4 + (jq - 2) * 2;
        cb[s][0][lane] = a00;  cb[s][1][lane] = a01;  cb[s][2][lane] = a0d;
        cb[s + 1][0][lane] = a10;  cb[s + 1][1][lane] = a11;  cb[s + 1][2][lane] = a1d;
    }
    __syncthreads();
    if (jq < 2) {
        int s = ih * 4 + jq * 2;
        a00 += cb[s][0][lane];  a01 += cb[s][1][lane];  a0d += cb[s][2][lane];
        a10 += cb[s + 1][0][lane];  a11 += cb[s + 1][1][lane];  a1d += cb[s + 1][2][lane];
    }
    __syncthreads();
    if (jq == 0) {
        int s = ih * 4;
        cb[s][0][lane] = a10;  cb[s][1][lane] = a11;  cb[s][2][lane] = a1d;
    } else if (jq == 1) {
        int s = ih * 4 + 1;
        cb[s][0][lane] = a00;  cb[s][1][lane] = a01;  cb[s][2][lane] = a0d;
    }
    __syncthreads();
    if (jq >= 2) return;
    f32x4 A0, A1, AD;
    if (jq == 0) {
        int s = ih * 4 + 1;
        A0 = a00 + cb[s][0][lane];
        A1 = a01 + cb[s][1][lane];
        AD = a0d + cb[s][2][lane];
    } else {
        int s = ih * 4;
        A0 = a10 + cb[s][0][lane];
        A1 = a11 + cb[s][1][lane];
        AD = a1d + cb[s][2][lane];
    }

    float* op = out + ((size_t)(b * NSZ) + iw + jq * 16) * (HH * ODIM) + h * ODIM + col;
#pragma unroll
    for (int r = 0; r < 4; r++) {
        int row = quad * 4 + r;
        float inv = 1.0f / AD[r];
        op[(size_t)row * (HH * ODIM)]      = fmaxf(A0[r] * inv, 0.f);
        op[(size_t)row * (HH * ODIM) + 16] = fmaxf(A1[r] * inv, 0.f);
    }
}

// ===========================================================================
// FUSED COOPERATIVE PATH. 512 blocks x 512 threads, LDS 25.4KB (<=32KB so
// 2 blocks/CU even under a 64KB/CU runtime LDS budget -> coop capacity 512).
// Phase 1: proj (2 units/blk; both halves share (b,h) => ONE shared W[h]
// staging) + adj bitmask (16 chunks/blk), stagger order by block parity.
// grid.sync() replaces the 2nd launch. Phase 2: 2 gat units/blk (R12 code,
// predicated epilogue).
// ===========================================================================
__global__ __launch_bounds__(512, 4) void k_fused(
        const float* __restrict__ x, const float* __restrict__ adj,
        const float* __restrict__ W, const float* __restrict__ a_src,
        const float* __restrict__ a_dst, unsigned* __restrict__ adjb,
        int4* __restrict__ whf, float* __restrict__ eap,
        unsigned short* __restrict__ ebe, unsigned short* __restrict__ ebe2,
        float* __restrict__ out) {
    __shared__ __align__(16) char smem[25600];
    int t = threadIdx.x;
    int blk = blockIdx.x;
    int half = t >> 8, tt = t & 255;

    // ======================= PHASE 1 =======================
    {
        float* wsl = (float*)smem;                                 // [128][33] f32, shared
        unsigned short* wld = (unsigned short*)(smem + 16896) + half * 2112; // per-half [64][33]

        auto do_proj = [&]() {
            int unit = blk * 2 + half;     // halves share b,h (32|2); differ in nt
            int b = unit >> 8;
            int h = (unit >> 5) & 7;
            int nt = unit & 31;
            int n0 = nt * 64;
            int w = tt >> 6, lane = tt & 63;
            int col = lane & 15, quad = lane >> 4;

            // stage W[h] once for both halves: 4096 floats by 512 threads
#pragma unroll
            for (int m = 0; m < 8; m++) {
                int idx = t + m * 512;
                wsl[(idx >> 5) * 33 + (idx & 31)] = W[(size_t)h * (FDIM * ODIM) + idx];
            }

            const float* xp = x + ((size_t)(b * NSZ) + n0 + w * 16 + col) * FDIM + quad * 8;
            int4 afr[4];
#pragma unroll
            for (int kt = 0; kt < 4; kt++) {
                float4 xa = *(const float4*)(xp + kt * 32);
                float4 xb = *(const float4*)(xp + kt * 32 + 4);
                afr[kt] = make_int4((int)hpack(xa.x, xa.y), (int)hpack(xa.z, xa.w),
                                    (int)hpack(xb.x, xb.y), (int)hpack(xb.z, xb.w));
            }
            __syncthreads();

            f32x4 alo = {0.f, 0.f, 0.f, 0.f};
            f32x4 ahi = {0.f, 0.f, 0.f, 0.f};
#pragma unroll
            for (int kt = 0; kt < 4; kt++) {
                half8 a8 = __builtin_bit_cast(half8, afr[kt]);
#pragma unroll
                for (int ot = 0; ot < 2; ot++) {
                    unsigned d[4];
#pragma unroll
                    for (int jp = 0; jp < 4; jp++) {
                        float lo = wsl[(kt * 32 + quad * 8 + 2 * jp) * 33 + ot * 16 + col];
                        float hi = wsl[(kt * 32 + quad * 8 + 2 * jp + 1) * 33 + ot * 16 + col];
                        d[jp] = hpack(lo, hi);
                    }
                    int4 bf = make_int4((int)d[0], (int)d[1], (int)d[2], (int)d[3]);
                    if (ot == 0)
                        alo = __builtin_amdgcn_mfma_f32_16x16x32_f16(a8,
                                __builtin_bit_cast(half8, bf), alo, 0, 0, 0);
                    else
                        ahi = __builtin_amdgcn_mfma_f32_16x16x32_f16(a8,
                                __builtin_bit_cast(half8, bf), ahi, 0, 0, 0);
                }
            }

            float as0 = a_src[h * ODIM + col], as1 = a_src[h * ODIM + 16 + col];
            float ad0 = a_dst[h * ODIM + col], ad1 = a_dst[h * ODIM + 16 + col];
#pragma unroll
            for (int r = 0; r < 4; r++) {
                float pa = alo[r] * as0 + ahi[r] * as1;
                float pb = alo[r] * ad0 + ahi[r] * ad1;
#pragma unroll
                for (int mk = 1; mk <= 8; mk <<= 1) {
                    pa += __shfl_xor(pa, mk);
                    pb += __shfl_xor(pb, mk);
                }
                if (col == 0) {
                    size_t idx = (size_t)(b * HH + h) * NSZ + n0 + w * 16 + quad * 4 + r;
                    eap[idx]  = __expf(-0.8f * pa);
                    ebe[idx]  = (unsigned short)(hpack(__expf(pb - 2.f), 0.f) & 0xffffu);
                    ebe2[idx] = (unsigned short)(hpack(__expf(0.2f * pb - 2.f), 0.f) & 0xffffu);
                }
            }

#pragma unroll
            for (int r = 0; r < 4; r++) {
                wld[(w * 16 + quad * 4 + r) * 33 + col]      = (unsigned short)(hpack(alo[r], 0.f) & 0xffffu);
                wld[(w * 16 + quad * 4 + r) * 33 + col + 16] = (unsigned short)(hpack(ahi[r], 0.f) & 0xffffu);
            }
            __syncthreads();
            int jl = w >> 1, ot = w & 1;
            unsigned d[4];
#pragma unroll
            for (int jp = 0; jp < 4; jp++) {
                unsigned lo = wld[(jl * 32 + quad * 8 + 2 * jp) * 33 + ot * 16 + col];
                unsigned hi = wld[(jl * 32 + quad * 8 + 2 * jp + 1) * 33 + ot * 16 + col];
                d[jp] = (hi << 16) | lo;
            }
            int fragid = ((b * HH + h) * 64 + nt * 2 + jl) * 2 + ot;
            whf[(size_t)fragid * 64 + lane] = make_int4((int)d[0], (int)d[1], (int)d[2], (int)d[3]);
        };

        auto do_adj = [&]() {
#pragma unroll 4
            for (int it = 0; it < 16; it++) {
                int g = (blk * 16 + it) * 512 + t;
                int l = g & 7;
                int word = g >> 3;
                int wk = word & 63;
                int row = word >> 6;
                int i = row & (NSZ - 1);
                const float4 v = *(const float4*)&adj[(size_t)row * NSZ + wk * 32 + l * 4];
                unsigned m = 0;
                if (v.x > 0.f) m |= 1u << (l * 4 + 0);
                if (v.y > 0.f) m |= 1u << (l * 4 + 1);
                if (v.z > 0.f) m |= 1u << (l * 4 + 2);
                if (v.w > 0.f) m |= 1u << (l * 4 + 3);
                m |= (unsigned)__shfl_xor((int)m, 1);
                m |= (unsigned)__shfl_xor((int)m, 2);
                m |= (unsigned)__shfl_xor((int)m, 4);
                if (l == 0) {
                    int jb = i - wk * 32;
                    if (jb >= 0 && jb < 32) m |= 1u << jb;
                    adjb[word] = m;
                }
            }
        };

        if (blk & 1) { do_proj(); do_adj(); }
        else         { do_adj(); do_proj(); }
    }

    __threadfence();
    cg::this_grid().sync();
    __threadfence();

    // ======================= PHASE 2: gat x2 =======================
    unsigned short* eble = (unsigned short*)smem;            // f16 EB [2048]
    unsigned short* eblf = (unsigned short*)smem + 2048;     // f16 EB2[2048]
    f32x4 (*cb)[3][64] = (f32x4 (*)[3][64])smem;             // 8 x 3KB = 24KB
    unsigned (*mlut)[2] = (unsigned (*)[2])(smem + 24576);   // above cb

    int wave = t >> 6, lane = t & 63;
    int ih = wave >> 2, jq = wave & 3;
    int col = lane & 15, quad = lane >> 4, qsh = quad * 8;
    const int4 onesv = make_int4(0x3C003C00, 0x3C003C00, 0x3C003C00, 0x3C003C00);
    half8 hones = __builtin_bit_cast(half8, onesv);

    if (t < 16) {
        mlut[t][0] = ((t & 1) ? 0x0000FFFFu : 0u) | ((t & 2) ? 0xFFFF0000u : 0u);
        mlut[t][1] = ((t & 4) ? 0x0000FFFFu : 0u) | ((t & 8) ? 0xFFFF0000u : 0u);
    }

    for (int rep = 0; rep < 2; rep++) {
        __syncthreads();   // smem handoff (phase-1 / previous combine dead)
        int up = ((blk & 7) * 64 + (blk >> 3)) * 2 + rep;   // [0,1024) XCD swizzle
        int b = up >> 8;
        int h = (up >> 5) & 7;
        int i0 = (up & 31) * 64;
        size_t bh = (size_t)(b * HH + h);

        const float4* ege = (const float4*)(ebe + bh * NSZ);
        const float4* egf = (const float4*)(ebe2 + bh * NSZ);
        if (t < 256) ((float4*)eble)[t] = ege[t];
        else         ((float4*)eblf)[t - 256] = egf[t - 256];

        int iw = i0 + ih * 32;
        float Ra = eap[bh * NSZ + iw + col];
        float Rb = eap[bh * NSZ + iw + 16 + col];
        unsigned R20 = hpack(Ra, Ra);
        unsigned R21 = hpack(Rb, Rb);
        const char* mbase = (const char*)(adjb + ((size_t)(b * NSZ) + iw + col) * 64)
                            + (size_t)jq * 64;
        const int4* bfp = (const int4*)whf + bh * 8192 + (size_t)(jq * 16) * 128 + lane;

        f32x4 a00 = {0.f,0.f,0.f,0.f}, a01 = {0.f,0.f,0.f,0.f}, a0d = {0.f,0.f,0.f,0.f};
        f32x4 a10 = {0.f,0.f,0.f,0.f}, a11 = {0.f,0.f,0.f,0.f}, a1d = {0.f,0.f,0.f,0.f};

        __syncthreads();

        for (int g = 0; g < 4; g++) {
            uint4 m0 = *(const uint4*)(mbase + 0 * 4096 + g * 16);
            uint4 m1 = *(const uint4*)(mbase + 1 * 4096 + g * 16);
            int4 blo[4], bhi[4];
#pragma unroll
            for (int q = 0; q < 4; q++) {
                blo[q] = bfp[(g * 4 + q) * 128];
                bhi[q] = bfp[(g * 4 + q) * 128 + 64];
            }
            unsigned ma0[4] = {m0.x, m0.y, m0.z, m0.w};
            unsigned ma1[4] = {m1.x, m1.y, m1.z, m1.w};
#pragma unroll
            for (int q = 0; q < 4; q++) {
                int jt = jq * 16 + g * 4 + q;
                uint4 ef = *(const uint4*)&eble[jt * 32 + qsh];
                uint4 gf = *(const uint4*)&eblf[jt * 32 + qsh];
                half8 b0 = __builtin_bit_cast(half8, blo[q]);
                half8 b1 = __builtin_bit_cast(half8, bhi[q]);
                int4 f0 = pfrag16(R20, ef, gf, ma0[q] >> qsh, mlut);
                int4 f1 = pfrag16(R21, ef, gf, ma1[q] >> qsh, mlut);
                half8 af0 = __builtin_bit_cast(half8, f0);
                half8 af1 = __builtin_bit_cast(half8, f1);
                a00 = __builtin_amdgcn_mfma_f32_16x16x32_f16(af0, b0, a00, 0, 0, 0);
                a01 = __builtin_amdgcn_mfma_f32_16x16x32_f16(af0, b1, a01, 0, 0, 0);
                a0d = __builtin_amdgcn_mfma_f32_16x16x32_f16(af0, hones, a0d, 0, 0, 0);
                a10 = __builtin_amdgcn_mfma_f32_16x16x32_f16(af1, b0, a10, 0, 0, 0);
                a11 = __builtin_amdgcn_mfma_f32_16x16x32_f16(af1, b1, a11, 0, 0, 0);
                a1d = __builtin_amdgcn_mfma_f32_16x16x32_f16(af1, hones, a1d, 0, 0, 0);
            }
        }

        __syncthreads();
        if (jq >= 2) {
            int s = ih * 4 + (jq - 2) * 2;
            cb[s][0][lane] = a00;  cb[s][1][lane] = a01;  cb[s][2][lane] = a0d;
            cb[s + 1][0][lane] = a10;  cb[s + 1][1][lane] = a11;  cb[s + 1][2][lane] = a1d;
        }
        __syncthreads();
        if (jq < 2) {
            int s = ih * 4 + jq * 2;
            a00 += cb[s][0][lane];  a01 += cb[s][1][lane];  a0d += cb[s][2][lane];
            a10 += cb[s + 1][0][lane];  a11 += cb[s + 1][1][lane];  a1d += cb[s + 1][2][lane];
        }
        __syncthreads();
        if (jq == 0) {
            int s = ih * 4;
            cb[s][0][lane] = a10;  cb[s][1][lane] = a11;  cb[s][2][lane] = a1d;
        } else if (jq == 1) {
            int s = ih * 4 + 1;
            cb[s][0][lane] = a00;  cb[s][1][lane] = a01;  cb[s][2][lane] = a0d;
        }
        __syncthreads();
        if (jq < 2) {
            f32x4 A0, A1, AD;
            if (jq == 0) {
                int s = ih * 4 + 1;
                A0 = a00 + cb[s][0][lane];
                A1 = a01 + cb[s][1][lane];
                AD = a0d + cb[s][2][lane];
            } else {
                int s = ih * 4;
                A0 = a10 + cb[s][0][lane];
                A1 = a11 + cb[s][1][lane];
                AD = a1d + cb[s][2][lane];
            }
            float* op = out + ((size_t)(b * NSZ) + iw + jq * 16) * (HH * ODIM) + h * ODIM + col;
#pragma unroll
            for (int r = 0; r < 4; r++) {
                int row = quad * 4 + r;
                float inv = 1.0f / AD[r];
                op[(size_t)row * (HH * ODIM)]      = fmaxf(A0[r] * inv, 0.f);
                op[(size_t)row * (HH * ODIM) + 16] = fmaxf(A1[r] * inv, 0.f);
            }
        }
    }
}

extern "C" void kernel_launch(void* const* d_in, const int* in_sizes, int n_in,
                              void* d_out, int out_size, void* d_ws, size_t ws_size,
                              hipStream_t stream) {
    const float* x     = (const float*)d_in[0];
    const float* adj   = (const float*)d_in[1];
    const float* W     = (const float*)d_in[2];
    const float* a_src = (const float*)d_in[3];
    const float* a_dst = (const float*)d_in[4];
    float* out = (float*)d_out;

    float* ws = (float*)d_ws;
    float* eap            = ws + WS_EAP;
    unsigned short* ebe   = (unsigned short*)(ws + WS_EBP);
    unsigned short* ebe2  = (unsigned short*)(ws + WS_EBP + 65536);
    unsigned* adjb        = (unsigned*)(ws + WS_ADJB);
    int4* whf             = (int4*)(ws + WS_WHF);

    // cooperative capacity precheck (non-enqueuing -> graph-capture-safe);
    // cached across calls. Need >=2 blocks/CU x 256 CUs >= 512 blocks.
    static int coop_ok = -1;
    if (coop_ok < 0) {
        int nb = 0;
        hipError_t qe = hipOccupancyMaxActiveBlocksPerMultiprocessor(
            &nb, (const void*)k_fused, 512, 0);
        coop_ok = (qe == hipSuccess && nb >= 2) ? 1 : 0;
    }

    if (coop_ok) {
        void* args[] = {(void*)&x, (void*)&adj, (void*)&W, (void*)&a_src,
                        (void*)&a_dst, (void*)&adjb, (void*)&whf, (void*)&eap,
                        (void*)&ebe, (void*)&ebe2, (void*)&out};
        hipError_t e = hipLaunchCooperativeKernel((const void*)k_fused, dim3(512),
                                                  dim3(512), args, 0, stream);
        if (e == hipSuccess) return;
        coop_ok = 0;  // fall through to two-kernel path
    }

    // fallback: exact R12 two-kernel path (known-good)
    k_prep<<<dim3(1024 + 4096), dim3(256), 0, stream>>>(x, adj, W, a_src, a_dst,
                                                        adjb, whf, eap, ebe, ebe2);
    k_gat<<<dim3(BB * HH * (NSZ / 64)), dim3(512), 0, stream>>>(whf, eap, ebe, ebe2, adjb, out);
}